// Round 1
// 315.249 us; speedup vs baseline: 1.0606x; 1.0606x over previous
//
#include <hip/hip_runtime.h>
#include <stdint.h>

#define BATCH 4096
#define NTX   4096   // NT*NX flattened sites
#define NH    2048   // N_HALF
#define KDIM  2048

// ---- dual-GEMM 8-phase geometry (m201-style counted-vmcnt schedule) ----
#define BM 256
#define BN 128
#define BK 64
#define THREADS 512
#define NITER (KDIM / BK)   // 32 K-tiles

// per-buffer elem offsets (unsigned short elems)
#define A_OFF 0        // A: 256 rows x 64 k = 16384 elems (32 KiB)
#define S_OFF 16384    // S: 128 rows x 64 k =  8192 elems (16 KiB)
#define T_OFF 24576    // T: 128 rows x 64 k =  8192 elems (16 KiB)
#define BUF_E 32768    // 64 KiB per buffer; x2 buffers = 128 KiB LDS

typedef __bf16 bf16x8 __attribute__((ext_vector_type(8)));
typedef float  f32x4  __attribute__((ext_vector_type(4)));

// RNE float -> bf16
__device__ __forceinline__ unsigned short f2bf(float f) {
    union { float f; unsigned u; } v; v.f = f;
    unsigned u = v.u;
    unsigned r = u + 0x7fffu + ((u >> 16) & 1u);
    return (unsigned short)(r >> 16);
}

__device__ __forceinline__ float fast_tanh(float x) {
    float e = __expf(x + x);
    return 1.f - 2.f / (e + 1.f);
}

typedef __attribute__((address_space(1))) void gvoid;
typedef __attribute__((address_space(3))) void lvoid;

__device__ __forceinline__ void async16(const unsigned short* g, unsigned short* l) {
    __builtin_amdgcn_global_load_lds((gvoid*)(void*)g, (lvoid*)l, 16, 0, 0);
}

// Swizzled elem offset within one LDS array: rows are 64 elems (128 B),
// logical 8-elem chunk c (0..7) stored at phys chunk (c + R%8)%8.
// A wave's frag read = 16 rows x 4 chunks -> every bank exactly 2-deep
// (the free minimum for wave64 on 32 banks). kk=1 chunk = kk=0 elem-off ^ 32.
__device__ __forceinline__ int roff(int R, int c) {
    return R * BK + (((c) + (R & 7)) & 7) * 8;
}

// ---------------------------------------------------------------------------
// prep: split phi -> B-half bf16; convert W_s, W_t -> bf16; zero logdet slots
// ---------------------------------------------------------------------------
__global__ void prep(const float* __restrict__ phi,
                     const float* __restrict__ Wsf,
                     const float* __restrict__ Wtf,
                     unsigned short* __restrict__ Bbf,
                     unsigned short* __restrict__ Wsb,
                     unsigned short* __restrict__ Wtb,
                     float* __restrict__ out)
{
    const int tid    = blockIdx.x * blockDim.x + threadIdx.x;
    const int stride = gridDim.x * blockDim.x;

    const float4* p4 = (const float4*)phi;
    for (int i = tid; i < (BATCH * NH / 4); i += stride) {
        float4 u = p4[2 * i], v = p4[2 * i + 1];
        uint2 o;
        o.x = (unsigned)f2bf(u.x) | ((unsigned)f2bf(u.z) << 16);
        o.y = (unsigned)f2bf(v.x) | ((unsigned)f2bf(v.z) << 16);
        ((uint2*)Bbf)[i] = o;
    }

    const float4* ws4 = (const float4*)Wsf;
    const float4* wt4 = (const float4*)Wtf;
    for (int i = tid; i < (NH * KDIM / 8); i += stride) {
        float4 u = ws4[2 * i], v = ws4[2 * i + 1];
        uint4 o;
        o.x = (unsigned)f2bf(u.x) | ((unsigned)f2bf(u.y) << 16);
        o.y = (unsigned)f2bf(u.z) | ((unsigned)f2bf(u.w) << 16);
        o.z = (unsigned)f2bf(v.x) | ((unsigned)f2bf(v.y) << 16);
        o.w = (unsigned)f2bf(v.z) | ((unsigned)f2bf(v.w) << 16);
        ((uint4*)Wsb)[i] = o;
        u = wt4[2 * i]; v = wt4[2 * i + 1];
        o.x = (unsigned)f2bf(u.x) | ((unsigned)f2bf(u.y) << 16);
        o.y = (unsigned)f2bf(u.z) | ((unsigned)f2bf(u.w) << 16);
        o.z = (unsigned)f2bf(v.x) | ((unsigned)f2bf(v.y) << 16);
        o.w = (unsigned)f2bf(v.z) | ((unsigned)f2bf(v.w) << 16);
        ((uint4*)Wtb)[i] = o;
    }

    for (int i = tid; i < BATCH; i += stride) out[(size_t)BATCH * NTX + i] = 0.f;
}

// ---------------------------------------------------------------------------
// Dual GEMM + coupling epilogue, 8-phase counted-vmcnt schedule.
// Per K-tile (BK=64), 4 phases x 16 MFMA; A-frags shared between the s and t
// accumulator streams. One 16 KB staging unit issued per phase (2 async16 per
// thread): ph0->A0(next) ph1->A1(next) ph2->S(next) ph3->T(next).
// Counted waits ONLY at half-tile boundaries; vmcnt never drains to 0:
//   end ph1: vmcnt(4)  -> T(cur) landed  (leaves A0,A1(next) in flight)
//   end ph3: vmcnt(2)  -> A0,A1,S(next) landed (leaves T(next) in flight)
// Raw s_barrier pairs per phase (no __syncthreads -> no vmcnt(0) drain).
// Overwrite hazards: every slot staged at tile t+1 was last ds_read >=3
// barrier-pairs earlier (A,S read ph0/ph1; T read ph2/ph3 of tile t).
// ---------------------------------------------------------------------------
__global__ __launch_bounds__(THREADS, 2) void coupling_gemm(
    const unsigned short* __restrict__ X,
    const unsigned short* __restrict__ Wsb,
    const unsigned short* __restrict__ Wtb,
    const float* __restrict__ bs,
    const float* __restrict__ bt,
    const float* __restrict__ phi,
    float* __restrict__ out,
    unsigned short* __restrict__ Xout,
    int parity)
{
    __shared__ unsigned short lds[2][BUF_E];   // 128 KiB

    const int tid = threadIdx.x;
    const int m0 = blockIdx.x * BM;
    const int n0 = blockIdx.y * BN;

    f32x4 acc_s[4][4], acc_t[4][4];
    const f32x4 zf = {0.f, 0.f, 0.f, 0.f};
#pragma unroll
    for (int i = 0; i < 4; i++)
#pragma unroll
        for (int j = 0; j < 4; j++) { acc_s[i][j] = zf; acc_t[i][j] = zf; }

    // staging: thread tid owns linear LDS bytes tid*16 within each 8 KB
    // half-unit (global_load_lds dest must be linear); the GLOBAL source is
    // inverse-swizzled so swizzled reads see the right data (rule: both-sides).
    const int srow = tid >> 3;                        // 0..63 (row within half-unit)
    const int cg   = ((tid & 7) - (srow & 7)) & 7;    // logical k-chunk at this slot
    const unsigned short* Ag = X   + (size_t)(m0 + srow) * KDIM + cg * 8;
    const unsigned short* Sg = Wsb + (size_t)(n0 + srow) * KDIM + cg * 8;
    const unsigned short* Tg = Wtb + (size_t)(n0 + srow) * KDIM + cg * 8;
    const size_t r64  = (size_t)64  * KDIM;
    const size_t r128 = (size_t)128 * KDIM;
    const int lw = tid * 8;   // LDS elem offset of this thread's 16 B slot

    const int wave = tid >> 6;
    const int lane = tid & 63;
    const int wm = (wave >> 1) * 64;   // 4 M-waves x 64 rows
    const int wn = (wave & 1) * 64;    // 2 N-waves x 64 cols
    const int lrow = lane & 15;
    const int kc   = lane >> 4;

    // precomputed swizzled read offsets for kk=0; kk=1 = ^32 (phys chunk ^4)
    int aO[4], sO[4], tO[4];
#pragma unroll
    for (int i = 0; i < 4; i++) {
        aO[i] = A_OFF + roff(wm + i * 16 + lrow, kc);
        sO[i] = S_OFF + roff(wn + i * 16 + lrow, kc);
        tO[i] = T_OFF + roff(wn + i * 16 + lrow, kc);
    }

    // prologue: stage tile 0 (A0,A1,S,T = 8 loads); need A0,A1,S before ph0
    {
        unsigned short* b = &lds[0][0];
        async16(Ag,              b + A_OFF + lw);
        async16(Ag + r64,        b + A_OFF + 4096 + lw);
        async16(Ag + r128,       b + A_OFF + 8192 + lw);
        async16(Ag + r128 + r64, b + A_OFF + 12288 + lw);
        async16(Sg,              b + S_OFF + lw);
        async16(Sg + r64,        b + S_OFF + 4096 + lw);
        async16(Tg,              b + T_OFF + lw);
        async16(Tg + r64,        b + T_OFF + 4096 + lw);
    }
    asm volatile("s_waitcnt vmcnt(2)" ::: "memory");   // T(0) may stay in flight
    __builtin_amdgcn_s_barrier();

    for (int t = 0; t < NITER; ++t) {
        unsigned short* bc = &lds[t & 1][0];
        unsigned short* bx = &lds[(t & 1) ^ 1][0];
        const int k0n = (((t + 1) < NITER) ? (t + 1) : 0) * BK;  // clamp: wasted but safe

        bf16x8 a0[4], a1[4], f[4];

        // -------- phase 0: acc_s kk=0 ; stage A-half0(next)
#pragma unroll
        for (int i = 0; i < 4; i++) {
            a0[i] = *(const bf16x8*)(bc + aO[i]);
            f[i]  = *(const bf16x8*)(bc + sO[i]);
        }
        async16(Ag + k0n,       bx + A_OFF + lw);
        async16(Ag + k0n + r64, bx + A_OFF + 4096 + lw);
        __builtin_amdgcn_s_barrier();
        __builtin_amdgcn_s_setprio(1);
#pragma unroll
        for (int mi = 0; mi < 4; mi++)
#pragma unroll
            for (int ni = 0; ni < 4; ni++)
                acc_s[mi][ni] = __builtin_amdgcn_mfma_f32_16x16x32_bf16(
                    a0[mi], f[ni], acc_s[mi][ni], 0, 0, 0);
        __builtin_amdgcn_s_setprio(0);
        __builtin_amdgcn_s_barrier();

        // -------- phase 1: acc_s kk=1 ; stage A-half1(next)
#pragma unroll
        for (int i = 0; i < 4; i++) {
            a1[i] = *(const bf16x8*)(bc + (aO[i] ^ 32));
            f[i]  = *(const bf16x8*)(bc + (sO[i] ^ 32));
        }
        async16(Ag + k0n + r128,       bx + A_OFF + 8192 + lw);
        async16(Ag + k0n + r128 + r64, bx + A_OFF + 12288 + lw);
        __builtin_amdgcn_s_barrier();
        __builtin_amdgcn_s_setprio(1);
#pragma unroll
        for (int mi = 0; mi < 4; mi++)
#pragma unroll
            for (int ni = 0; ni < 4; ni++)
                acc_s[mi][ni] = __builtin_amdgcn_mfma_f32_16x16x32_bf16(
                    a1[mi], f[ni], acc_s[mi][ni], 0, 0, 0);
        __builtin_amdgcn_s_setprio(0);
        asm volatile("s_waitcnt vmcnt(4)" ::: "memory");  // T(cur) landed
        __builtin_amdgcn_s_barrier();

        // -------- phase 2: acc_t kk=0 (reuse a0) ; stage S(next)
#pragma unroll
        for (int i = 0; i < 4; i++)
            f[i] = *(const bf16x8*)(bc + tO[i]);
        async16(Sg + k0n,       bx + S_OFF + lw);
        async16(Sg + k0n + r64, bx + S_OFF + 4096 + lw);
        __builtin_amdgcn_s_barrier();
        __builtin_amdgcn_s_setprio(1);
#pragma unroll
        for (int mi = 0; mi < 4; mi++)
#pragma unroll
            for (int ni = 0; ni < 4; ni++)
                acc_t[mi][ni] = __builtin_amdgcn_mfma_f32_16x16x32_bf16(
                    a0[mi], f[ni], acc_t[mi][ni], 0, 0, 0);
        __builtin_amdgcn_s_setprio(0);
        __builtin_amdgcn_s_barrier();

        // -------- phase 3: acc_t kk=1 (reuse a1) ; stage T(next)
#pragma unroll
        for (int i = 0; i < 4; i++)
            f[i] = *(const bf16x8*)(bc + (tO[i] ^ 32));
        async16(Tg + k0n,       bx + T_OFF + lw);
        async16(Tg + k0n + r64, bx + T_OFF + 4096 + lw);
        __builtin_amdgcn_s_barrier();
        __builtin_amdgcn_s_setprio(1);
#pragma unroll
        for (int mi = 0; mi < 4; mi++)
#pragma unroll
            for (int ni = 0; ni < 4; ni++)
                acc_t[mi][ni] = __builtin_amdgcn_mfma_f32_16x16x32_bf16(
                    a1[mi], f[ni], acc_t[mi][ni], 0, 0, 0);
        __builtin_amdgcn_s_setprio(0);
        asm volatile("s_waitcnt vmcnt(2)" ::: "memory");  // A0,A1,S(next) landed
        __builtin_amdgcn_s_barrier();
    }

    // epilogue: C/D layout col=lane&15, row=(lane>>4)*4+reg
    float* ldslot = out + (size_t)BATCH * NTX;
#pragma unroll
    for (int mi = 0; mi < 4; mi++) {
#pragma unroll
        for (int r = 0; r < 4; r++) {
            const int brow = m0 + wm + mi * 16 + (lane >> 4) * 4 + r;
            float ssum = 0.f;
#pragma unroll
            for (int ni = 0; ni < 4; ni++) {
                const int n = n0 + wn + ni * 16 + lrow;
                float s  = fast_tanh(acc_s[mi][ni][r] + bs[n]);
                float tv = acc_t[mi][ni][r] + bt[n];
                const size_t oidx = (size_t)brow * NTX + 2 * n + parity;
                float val = fmaf(phi[oidx], __expf(s), tv);
                out[oidx] = val;
                if (Xout) Xout[(size_t)brow * NH + n] = f2bf(val);
                ssum += s;
            }
            ssum += __shfl_xor(ssum, 1);
            ssum += __shfl_xor(ssum, 2);
            ssum += __shfl_xor(ssum, 4);
            ssum += __shfl_xor(ssum, 8);
            if (lrow == 0) atomicAdd(ldslot + brow, ssum);
        }
    }
}

extern "C" void kernel_launch(void* const* d_in, const int* in_sizes, int n_in,
                              void* d_out, int out_size, void* d_ws, size_t ws_size,
                              hipStream_t stream) {
    const float* phi = (const float*)d_in[0];
    const float* Wsf = (const float*)d_in[1];
    const float* bs  = (const float*)d_in[2];
    const float* Wtf = (const float*)d_in[3];
    const float* bt  = (const float*)d_in[4];
    float* out = (float*)d_out;

    char* ws = (char*)d_ws;
    unsigned short* Bbf  = (unsigned short*)(ws);                 // 16 MiB
    unsigned short* Apbf = (unsigned short*)(ws + 16777216);      // 16 MiB
    unsigned short* Wsb  = (unsigned short*)(ws + 33554432);      //  8 MiB
    unsigned short* Wtb  = (unsigned short*)(ws + 41943040);      //  8 MiB

    prep<<<1024, 256, 0, stream>>>(phi, Wsf, Wtf, Bbf, Wsb, Wtb, out);

    // coupling 1: A' = A*exp(s(B)) + t(B)  (A at odd flat slots: parity=1)
    coupling_gemm<<<dim3(16, 16), THREADS, 0, stream>>>(
        Bbf, Wsb, Wtb, bs, bt, phi, out, Apbf, 1);

    // coupling 2: B' = B*exp(s(A')) + t(A') (B at even flat slots: parity=0)
    coupling_gemm<<<dim3(16, 16), THREADS, 0, stream>>>(
        Apbf, Wsb, Wtb, bs, bt, phi, out, nullptr, 0);
}